// Round 8
// baseline (267.961 us; speedup 1.0000x reference)
//
#include <hip/hip_runtime.h>
#include <hip/hip_bf16.h>
#include <math.h>

#define N_NODESC 50000
#define N_EDGESC 500000
#define E_TOT    (N_EDGESC + N_NODESC)   // 550000 (self-loops appended)
#define IN_CH 128
#define HID 32
#define HEADS 4
#define HC (HEADS*HID)    // 128
#define OUT_CH 64
#define NEG_SLOPE 0.2f
#define NB_SCAN 196        // ceil(50000/256)
#define N_STRIPS (N_NODESC/16)   // 3125 exact

typedef unsigned short u16;
typedef __attribute__((ext_vector_type(8))) short short8;        // 8 bf16 (4 VGPRs)
typedef __attribute__((ext_vector_type(4))) float floatx4;       // 4 fp32 acc

// manual bf16 round-to-nearest-even
__device__ __forceinline__ u16 f2bf(float f){
  unsigned u = __float_as_uint(f);
  return (u16)((u + 0x7FFFu + ((u >> 16) & 1u)) >> 16);
}
__device__ __forceinline__ float bf2f(u16 b){ return __uint_as_float(((unsigned)b) << 16); }
__device__ __forceinline__ float bflo(unsigned q){ return __uint_as_float(q << 16); }
__device__ __forceinline__ float bfhi(unsigned q){ return __uint_as_float(q & 0xFFFF0000u); }
// lrelu(v) = max(v, 0.2v)  (valid since 0 < slope < 1)
__device__ __forceinline__ float lrelu(float v){ return fmaxf(v, NEG_SLOPE*v); }

__device__ __forceinline__ void edge_sd(const int* __restrict__ ei, int e, int& s, int& d){
  if (e < N_EDGESC){ s = ei[e]; d = ei[N_EDGESC + e]; }
  else { s = e - N_EDGESC; d = s; }
}

// ---------------- CSR build ----------------
__global__ void k_zero_deg(int* __restrict__ deg){
  int i = blockIdx.x*blockDim.x + threadIdx.x;
  if (i < N_NODESC) deg[i] = 0;
}

__global__ void k_hist(const int* __restrict__ ei, int* __restrict__ deg){
  int e = blockIdx.x*blockDim.x + threadIdx.x;
  if (e >= E_TOT) return;
  int s, d; edge_sd(ei, e, s, d);
  atomicAdd(&deg[d], 1);
}

__global__ void k_scan_a(const int* __restrict__ deg, int* __restrict__ rs,
                         int* __restrict__ bsum){
  __shared__ int sh[256];
  int i = blockIdx.x*256 + threadIdx.x;
  int v = (i < N_NODESC) ? deg[i] : 0;
  sh[threadIdx.x] = v;
  __syncthreads();
  for (int off=1; off<256; off<<=1){
    int t = (threadIdx.x >= off) ? sh[threadIdx.x-off] : 0;
    __syncthreads();
    sh[threadIdx.x] += t;
    __syncthreads();
  }
  if (i < N_NODESC) rs[i] = sh[threadIdx.x] - v;
  if (threadIdx.x == 255) bsum[blockIdx.x] = sh[255];
}

__global__ void k_scan_b(int* __restrict__ bsum){
  __shared__ int sh[256];
  int v = (threadIdx.x < NB_SCAN) ? bsum[threadIdx.x] : 0;
  sh[threadIdx.x] = v;
  __syncthreads();
  for (int off=1; off<256; off<<=1){
    int t = (threadIdx.x >= off) ? sh[threadIdx.x-off] : 0;
    __syncthreads();
    sh[threadIdx.x] += t;
    __syncthreads();
  }
  if (threadIdx.x < NB_SCAN) bsum[threadIdx.x] = sh[threadIdx.x] - v;
}

__global__ void k_scan_c(int* __restrict__ rs, const int* __restrict__ bsum,
                         int* __restrict__ cursor){
  int i = blockIdx.x*256 + threadIdx.x;
  if (i >= N_NODESC) return;
  int v = rs[i] + bsum[blockIdx.x];
  rs[i] = v;
  cursor[i] = v;
}

__global__ void k_fill(const int* __restrict__ ei, int* __restrict__ cursor,
                       int* __restrict__ csrc){
  int e = blockIdx.x*blockDim.x + threadIdx.x;
  if (e >= E_TOT) return;
  int s, d; edge_sd(ei, e, s, d);
  int pos = atomicAdd(&cursor[d], 1);
  csrc[pos] = s;
}

// ---------------- split x into bf16 hi/lo (A operand for gemm1) ----------------
__global__ void k_split(const float* __restrict__ X, u16* __restrict__ hi,
                        u16* __restrict__ lo, int total4){
  int i = blockIdx.x*blockDim.x + threadIdx.x;
  if (i >= total4) return;
  float4 v = ((const float4*)X)[i];
  ushort4 h, l;
  h.x = f2bf(v.x); l.x = f2bf(v.x - bf2f(h.x));
  h.y = f2bf(v.y); l.y = f2bf(v.y - bf2f(h.y));
  h.z = f2bf(v.z); l.z = f2bf(v.z - bf2f(h.z));
  h.w = f2bf(v.w); l.w = f2bf(v.w - bf2f(h.w));
  ((ushort4*)hi)[i] = h;
  ((ushort4*)lo)[i] = l;
}

// ---------------- weight prep (bf16 hi only) ----------------
__global__ void k_prep_all(const float* __restrict__ W1l, const float* __restrict__ W1r,
                           const float* __restrict__ W2l, const float* __restrict__ W2r,
                           u16* __restrict__ w1lh, u16* __restrict__ w1rh,
                           u16* __restrict__ w2lh, u16* __restrict__ w2rh){
  int b = blockIdx.x;
  const float* W; u16 *Th; int N, base;
  if (b < 8)      { W=W1l; Th=w1lh; N=HC;     base=b;    }
  else if (b < 16){ W=W1r; Th=w1rh; N=HC;     base=b-8;  }
  else if (b < 20){ W=W2l; Th=w2lh; N=OUT_CH; base=b-16; }
  else            { W=W2r; Th=w2rh; N=OUT_CH; base=b-20; }
  int tid = base*256 + threadIdx.x;
  int lane = tid & 63;
  int t = (tid >> 6) & 3;
  int c = tid >> 8;
  int k0 = t*32 + (lane>>4)*8;
  int n  = c*16 + (lane&15);
  #pragma unroll
  for (int j=0;j<8;j++){
    Th[(size_t)tid*8 + j] = f2bf(W[(size_t)(k0+j)*N + n]);
  }
}

// ---------------- register-B MFMA GEMM ----------------
template<int NCW, int SPB>
__launch_bounds__(256, 2)
__global__ void k_gemm_regB(const u16* __restrict__ Ahi, const u16* __restrict__ Alo,
                            const u16* __restrict__ BlT, const u16* __restrict__ BrT,
                            u16* __restrict__ Olb, float* __restrict__ Or){
  constexpr int NLD = 2*NCW*16;
  int wave = threadIdx.x >> 6, lane = threadIdx.x & 63;
  int m = lane & 15, quad = lane >> 4;
  bool isl = (wave < 2);
  int ctbase = (isl ? wave : wave - 2) * NCW;
  const u16* __restrict__ BT = isl ? BlT : BrT;

  short8 breg[NCW][4];
  #pragma unroll
  for (int c=0;c<NCW;c++)
    #pragma unroll
    for (int t=0;t<4;t++)
      breg[c][t] = *(const short8*)(BT + ((size_t)(((ctbase+c)*4 + t)*64) + lane)*8);

  int strip0 = blockIdx.x * SPB;
  short8 ah[2][4], al[2][4];

  {
    const u16* p1 = Ahi + (size_t)(strip0*16 + m)*128 + quad*8;
    const u16* p2 = Alo + (size_t)(strip0*16 + m)*128 + quad*8;
    #pragma unroll
    for (int t=0;t<4;t++){
      ah[0][t] = *(const short8*)(p1 + t*32);
      al[0][t] = *(const short8*)(p2 + t*32);
    }
  }

  #pragma unroll
  for (int i=0;i<SPB;i++){
    int s = strip0 + i;
    if (s >= N_STRIPS) break;
    if (i+1 < SPB && s+1 < N_STRIPS){
      const u16* p1 = Ahi + (size_t)((s+1)*16 + m)*128 + quad*8;
      const u16* p2 = Alo + (size_t)((s+1)*16 + m)*128 + quad*8;
      #pragma unroll
      for (int t=0;t<4;t++){
        ah[(i+1)&1][t] = *(const short8*)(p1 + t*32);
        al[(i+1)&1][t] = *(const short8*)(p2 + t*32);
      }
    }
    const int b = i&1;
    floatx4 acc[NCW];
    #pragma unroll
    for (int c=0;c<NCW;c++) acc[c] = (floatx4){0.f,0.f,0.f,0.f};
    #pragma unroll
    for (int t=0;t<4;t++){
      #pragma unroll
      for (int c=0;c<NCW;c++){
        acc[c] = __builtin_amdgcn_mfma_f32_16x16x32_bf16(ah[b][t], breg[c][t], acc[c], 0,0,0);
        acc[c] = __builtin_amdgcn_mfma_f32_16x16x32_bf16(al[b][t], breg[c][t], acc[c], 0,0,0);
      }
    }
    int row0 = s*16;
    if (isl){
      #pragma unroll
      for (int c=0;c<NCW;c++)
        #pragma unroll
        for (int r=0;r<4;r++)
          Olb[(size_t)(row0 + quad*4 + r)*NLD + (ctbase+c)*16 + m] = f2bf(acc[c][r]);
    } else {
      #pragma unroll
      for (int c=0;c<NCW;c++)
        #pragma unroll
        for (int r=0;r<4;r++)
          Or[(size_t)(row0 + quad*4 + r)*NLD + (ctbase+c)*16 + m] = acc[c][r];
    }
  }
}

// ---------------- layer 1 fused (v3): batched gathers, MLP=4 ----------------
// Wave per dst. Up to 64 neighbor indices loaded in ONE coalesced load and
// broadcast via __shfl. 4 groups x 16 lanes; per 16-edge batch each group
// issues 4 independent gathers (uint4=16B, lane covers ch 8l..8l+7, head=l>>2)
// before consuming. No max-subtraction (scores O(5); alpha shift-invariant).
__global__ void k_fused1(const int* __restrict__ rs, const int* __restrict__ deg,
                         const int* __restrict__ csrc, const u16* __restrict__ xlb,
                         const float* __restrict__ xr, const float* __restrict__ att,
                         const float* __restrict__ b1,
                         u16* __restrict__ Hhi, u16* __restrict__ Hlo){
  int wave = threadIdx.x >> 6;
  int lane = threadIdx.x & 63;
  int d = blockIdx.x*4 + wave;
  if (d >= N_NODESC) return;
  int g = lane >> 4;        // edge-slot group
  int l = lane & 15;        // channel slice: 8l..8l+7

  float xrv[8], atv[8];
  {
    float4 a = *(const float4*)(xr + (size_t)d*HC + 8*l);
    float4 b = *(const float4*)(xr + (size_t)d*HC + 8*l + 4);
    xrv[0]=a.x; xrv[1]=a.y; xrv[2]=a.z; xrv[3]=a.w;
    xrv[4]=b.x; xrv[5]=b.y; xrv[6]=b.z; xrv[7]=b.w;
    float4 c = *(const float4*)(att + 8*l);
    float4 e = *(const float4*)(att + 8*l + 4);
    atv[0]=c.x; atv[1]=c.y; atv[2]=c.z; atv[3]=c.w;
    atv[4]=e.x; atv[5]=e.y; atv[6]=e.z; atv[7]=e.w;
  }

  int start = rs[d], degd = deg[d];

  float acc[8];
  #pragma unroll
  for (int j=0;j<8;j++) acc[j] = 0.f;
  float den = 0.f;

  for (int base = 0; base < degd; base += 64){
    int nrem = degd - base;
    int nb = (nrem < 64) ? nrem : 64;
    int idx = csrc[start + base + ((lane < nb) ? lane : 0)];   // coalesced (deg>=1)
    for (int b = 0; b < nb; b += 16){
      uint4 qv[4];
      int val[4];
      #pragma unroll
      for (int k=0;k<4;k++){
        int ee = b + g*4 + k;                 // < 64 always
        int s = __shfl(idx, ee);
        val[k] = (ee < nb);
        qv[k] = *(const uint4*)(xlb + (size_t)s*HC + 8*l);   // 16B gather
      }
      #pragma unroll
      for (int k=0;k<4;k++){
        float xv[8];
        xv[0]=bflo(qv[k].x); xv[1]=bfhi(qv[k].x);
        xv[2]=bflo(qv[k].y); xv[3]=bfhi(qv[k].y);
        xv[4]=bflo(qv[k].z); xv[5]=bfhi(qv[k].z);
        xv[6]=bflo(qv[k].w); xv[7]=bfhi(qv[k].w);
        float sc = 0.f;
        #pragma unroll
        for (int j=0;j<8;j++) sc = fmaf(lrelu(xv[j] + xrv[j]), atv[j], sc);
        sc += __shfl_xor(sc, 1);
        sc += __shfl_xor(sc, 2);              // per-head sum (4-lane span)
        float p = val[k] ? __expf(sc) : 0.f;
        den += p;
        #pragma unroll
        for (int j=0;j<8;j++) acc[j] = fmaf(p, xv[j], acc[j]);
      }
    }
  }

  // cross-group combine
  #pragma unroll
  for (int j=0;j<8;j++){
    acc[j] += __shfl_xor(acc[j], 16);
    acc[j] += __shfl_xor(acc[j], 32);
  }
  den += __shfl_xor(den, 16);
  den += __shfl_xor(den, 32);

  if (g == 0){
    float bv[8];
    float4 a = *(const float4*)(b1 + 8*l);
    float4 b = *(const float4*)(b1 + 8*l + 4);
    bv[0]=a.x; bv[1]=a.y; bv[2]=a.z; bv[3]=a.w;
    bv[4]=b.x; bv[5]=b.y; bv[6]=b.z; bv[7]=b.w;
    float inv = 1.f / (den + 1e-16f);
    ushort4 oh, ol;
    u16 ohv[8], olv[8];
    #pragma unroll
    for (int j=0;j<8;j++){
      float o = acc[j]*inv + bv[j];
      o = (o > 0.f) ? o : (__expf(o) - 1.f);
      u16 h = f2bf(o);
      ohv[j] = h;
      olv[j] = f2bf(o - bf2f(h));
    }
    ushort4 h0 = {ohv[0],ohv[1],ohv[2],ohv[3]}, h1 = {ohv[4],ohv[5],ohv[6],ohv[7]};
    ushort4 l0 = {olv[0],olv[1],olv[2],olv[3]}, l1 = {olv[4],olv[5],olv[6],olv[7]};
    *(ushort4*)(Hhi + (size_t)d*HC + 8*l)     = h0;
    *(ushort4*)(Hhi + (size_t)d*HC + 8*l + 4) = h1;
    *(ushort4*)(Hlo + (size_t)d*HC + 8*l)     = l0;
    *(ushort4*)(Hlo + (size_t)d*HC + 8*l + 4) = l1;
  }
}

// ---------------- layer 2 fused (v3): batched gathers, MLP=4 ----------------
// Wave per dst; 4 groups x 16 lanes; lane covers ch 4l..4l+3 (uint2=8B gather);
// score reduced over 16 lanes (4 shfl); heads=1.
__global__ void k_fused2(const int* __restrict__ rs, const int* __restrict__ deg,
                         const int* __restrict__ csrc, const u16* __restrict__ xlb,
                         const float* __restrict__ xr, const float* __restrict__ att,
                         const float* __restrict__ b2, float* __restrict__ out){
  int wave = threadIdx.x >> 6;
  int lane = threadIdx.x & 63;
  int d = blockIdx.x*4 + wave;
  if (d >= N_NODESC) return;
  int g = lane >> 4;
  int l = lane & 15;        // channels 4l..4l+3

  float xrv[4], atv[4];
  {
    float4 a = *(const float4*)(xr + (size_t)d*OUT_CH + 4*l);
    xrv[0]=a.x; xrv[1]=a.y; xrv[2]=a.z; xrv[3]=a.w;
    float4 c = *(const float4*)(att + 4*l);
    atv[0]=c.x; atv[1]=c.y; atv[2]=c.z; atv[3]=c.w;
  }

  int start = rs[d], degd = deg[d];

  float acc[4] = {0.f,0.f,0.f,0.f};
  float den = 0.f;

  for (int base = 0; base < degd; base += 64){
    int nrem = degd - base;
    int nb = (nrem < 64) ? nrem : 64;
    int idx = csrc[start + base + ((lane < nb) ? lane : 0)];
    for (int b = 0; b < nb; b += 16){
      uint2 qv[4];
      int val[4];
      #pragma unroll
      for (int k=0;k<4;k++){
        int ee = b + g*4 + k;
        int s = __shfl(idx, ee);
        val[k] = (ee < nb);
        qv[k] = *(const uint2*)(xlb + (size_t)s*OUT_CH + 4*l);   // 8B gather
      }
      #pragma unroll
      for (int k=0;k<4;k++){
        float xv[4];
        xv[0]=bflo(qv[k].x); xv[1]=bfhi(qv[k].x);
        xv[2]=bflo(qv[k].y); xv[3]=bfhi(qv[k].y);
        float sc = 0.f;
        #pragma unroll
        for (int j=0;j<4;j++) sc = fmaf(lrelu(xv[j] + xrv[j]), atv[j], sc);
        sc += __shfl_xor(sc, 1);
        sc += __shfl_xor(sc, 2);
        sc += __shfl_xor(sc, 4);
        sc += __shfl_xor(sc, 8);              // full 64-ch sum
        float p = val[k] ? __expf(sc) : 0.f;
        den += p;
        #pragma unroll
        for (int j=0;j<4;j++) acc[j] = fmaf(p, xv[j], acc[j]);
      }
    }
  }

  #pragma unroll
  for (int j=0;j<4;j++){
    acc[j] += __shfl_xor(acc[j], 16);
    acc[j] += __shfl_xor(acc[j], 32);
  }
  den += __shfl_xor(den, 16);
  den += __shfl_xor(den, 32);

  if (g == 0){
    float4 bvv = *(const float4*)(b2 + 4*l);
    float inv = 1.f / (den + 1e-16f);
    float4 o;
    o.x = acc[0]*inv + bvv.x;
    o.y = acc[1]*inv + bvv.y;
    o.z = acc[2]*inv + bvv.z;
    o.w = acc[3]*inv + bvv.w;
    *(float4*)(out + (size_t)d*OUT_CH + 4*l) = o;
  }
}

extern "C" void kernel_launch(void* const* d_in, const int* in_sizes, int n_in,
                              void* d_out, int out_size, void* d_ws, size_t ws_size,
                              hipStream_t stream) {
  const float* x    = (const float*)d_in[0];
  const int*   ei   = (const int*)d_in[1];
  const float* W1l  = (const float*)d_in[2];
  const float* W1r  = (const float*)d_in[3];
  const float* att1 = (const float*)d_in[4];
  const float* b1   = (const float*)d_in[5];
  const float* W2l  = (const float*)d_in[6];
  const float* W2r  = (const float*)d_in[7];
  const float* att2 = (const float*)d_in[8];
  const float* b2   = (const float*)d_in[9];
  float* out = (float*)d_out;

  // workspace layout (units of float; offsets multiples of 4 -> 16B aligned)
  float* ws = (float*)d_ws;
  size_t off = 0;
  float* xr1 = ws + off; off += (size_t)N_NODESC*HC;          // fp32 [N x 128]
  float* xr2 = ws + off; off += (size_t)N_NODESC*OUT_CH;      // fp32 [N x 64]
  u16* xl1b = (u16*)(ws + off); off += (size_t)N_NODESC*HC/2;     // bf16 gather [N x 128]
  u16* xl2b = (u16*)(ws + off); off += (size_t)N_NODESC*OUT_CH/2; // bf16 gather [N x 64]
  u16* xhi = (u16*)(ws + off); off += (size_t)N_NODESC*HC/2;  // A for gemm1
  u16* xlo = (u16*)(ws + off); off += (size_t)N_NODESC*HC/2;
  u16* hhi = (u16*)(ws + off); off += (size_t)N_NODESC*HC/2;  // A for gemm2
  u16* hlo = (u16*)(ws + off); off += (size_t)N_NODESC*HC/2;
  u16* w1lh = (u16*)(ws + off); off += IN_CH*HC/2;
  u16* w1rh = (u16*)(ws + off); off += IN_CH*HC/2;
  u16* w2lh = (u16*)(ws + off); off += HC*OUT_CH/2;
  u16* w2rh = (u16*)(ws + off); off += HC*OUT_CH/2;
  int* deg    = (int*)(ws + off); off += N_NODESC;
  int* rs     = (int*)(ws + off); off += N_NODESC;
  int* cursor = (int*)(ws + off); off += N_NODESC;
  int* bsum   = (int*)(ws + off); off += 256;
  int* csrc   = (int*)(ws + off); off += E_TOT;

  // ---- CSR build (graph identical for both layers) ----
  k_zero_deg<<<(N_NODESC+255)/256, 256, 0, stream>>>(deg);
  k_hist<<<(E_TOT+255)/256, 256, 0, stream>>>(ei, deg);
  k_scan_a<<<NB_SCAN, 256, 0, stream>>>(deg, rs, bsum);
  k_scan_b<<<1, 256, 0, stream>>>(bsum);
  k_scan_c<<<NB_SCAN, 256, 0, stream>>>(rs, bsum, cursor);
  k_fill<<<(E_TOT+255)/256, 256, 0, stream>>>(ei, cursor, csrc);

  // ---- input split + weight packing ----
  k_split<<<((N_NODESC*HC/4)+255)/256, 256, 0, stream>>>(x, xhi, xlo, N_NODESC*HC/4);
  k_prep_all<<<24, 256, 0, stream>>>(W1l, W1r, W2l, W2r, w1lh, w1rh, w2lh, w2rh);

  const int NB_G = (N_STRIPS + 3)/4;   // SPB=4
  // ---- layer 1 ----
  k_gemm_regB<4,4><<<NB_G, 256, 0, stream>>>(xhi, xlo, w1lh, w1rh, xl1b, xr1);
  k_fused1<<<(N_NODESC+3)/4, 256, 0, stream>>>(rs, deg, csrc, xl1b, xr1, att1, b1, hhi, hlo);

  // ---- layer 2 ----
  k_gemm_regB<2,4><<<NB_G, 256, 0, stream>>>(hhi, hlo, w2lh, w2rh, xl2b, xr2);
  k_fused2<<<(N_NODESC+3)/4, 256, 0, stream>>>(rs, deg, csrc, xl2b, xr2, att2, b2, out);
}

// Round 9
// 264.895 us; speedup vs baseline: 1.0116x; 1.0116x over previous
//
#include <hip/hip_runtime.h>
#include <hip/hip_bf16.h>
#include <math.h>

#define N_NODESC 50000
#define N_EDGESC 500000
#define E_TOT    (N_EDGESC + N_NODESC)   // 550000 (self-loops appended)
#define IN_CH 128
#define HID 32
#define HEADS 4
#define HC (HEADS*HID)    // 128
#define OUT_CH 64
#define NEG_SLOPE 0.2f
#define NB_SCAN 196        // ceil(50000/256)
#define N_STRIPS (N_NODESC/16)   // 3125 exact

typedef unsigned short u16;
typedef __attribute__((ext_vector_type(8))) short short8;          // 8 bf16 (4 VGPRs)
typedef __attribute__((ext_vector_type(8))) unsigned short ushort8v;
typedef __attribute__((ext_vector_type(4))) unsigned short ushort4v;
typedef __attribute__((ext_vector_type(4))) float floatx4;         // 4 fp32 acc

// manual bf16 round-to-nearest-even
__device__ __forceinline__ u16 f2bf(float f){
  unsigned u = __float_as_uint(f);
  return (u16)((u + 0x7FFFu + ((u >> 16) & 1u)) >> 16);
}
__device__ __forceinline__ float bf2f(u16 b){ return __uint_as_float(((unsigned)b) << 16); }
__device__ __forceinline__ float bflo(unsigned q){ return __uint_as_float(q << 16); }
__device__ __forceinline__ float bfhi(unsigned q){ return __uint_as_float(q & 0xFFFF0000u); }
// lrelu(v) = max(v, 0.2v)  (valid since 0 < slope < 1)
__device__ __forceinline__ float lrelu(float v){ return fmaxf(v, NEG_SLOPE*v); }

__device__ __forceinline__ void edge_sd(const int* __restrict__ ei, int e, int& s, int& d){
  if (e < N_EDGESC){ s = ei[e]; d = ei[N_EDGESC + e]; }
  else { s = e - N_EDGESC; d = s; }
}

// ---------------- misc: zero deg + weight prep + x split, one launch ----------------
// blocks 0..195: zero deg; 196..219: weight prep; 220..: x hi/lo split.
__global__ void k_misc(int* __restrict__ deg,
                       const float* __restrict__ X, u16* __restrict__ xhi, u16* __restrict__ xlo,
                       const float* __restrict__ W1l, const float* __restrict__ W1r,
                       const float* __restrict__ W2l, const float* __restrict__ W2r,
                       u16* __restrict__ w1lh, u16* __restrict__ w1rh,
                       u16* __restrict__ w2lh, u16* __restrict__ w2rh){
  int b = blockIdx.x;
  if (b < 196){
    int i = b*256 + threadIdx.x;
    if (i < N_NODESC) deg[i] = 0;
  } else if (b < 220){
    int bb = b - 196;
    const float* W; u16 *Th; int N, base;
    if (bb < 8)      { W=W1l; Th=w1lh; N=HC;     base=bb;    }
    else if (bb < 16){ W=W1r; Th=w1rh; N=HC;     base=bb-8;  }
    else if (bb < 20){ W=W2l; Th=w2lh; N=OUT_CH; base=bb-16; }
    else             { W=W2r; Th=w2rh; N=OUT_CH; base=bb-20; }
    // packed idx = (((c*4 + t)*64) + lane)*8 + j
    // value      = W[(t*32 + (lane>>4)*8 + j)*N + c*16 + (lane&15)]
    int tid = base*256 + threadIdx.x;
    int lane = tid & 63;
    int t = (tid >> 6) & 3;
    int c = tid >> 8;
    int k0 = t*32 + (lane>>4)*8;
    int n  = c*16 + (lane&15);
    #pragma unroll
    for (int j=0;j<8;j++){
      Th[(size_t)tid*8 + j] = f2bf(W[(size_t)(k0+j)*N + n]);
    }
  } else {
    int i = (b-220)*256 + threadIdx.x;
    if (i < N_NODESC*HC/4){
      float4 v = ((const float4*)X)[i];
      ushort4 h, l;
      h.x = f2bf(v.x); l.x = f2bf(v.x - bf2f(h.x));
      h.y = f2bf(v.y); l.y = f2bf(v.y - bf2f(h.y));
      h.z = f2bf(v.z); l.z = f2bf(v.z - bf2f(h.z));
      h.w = f2bf(v.w); l.w = f2bf(v.w - bf2f(h.w));
      ((ushort4*)xhi)[i] = h;
      ((ushort4*)xlo)[i] = l;
    }
  }
}

// ---------------- CSR build ----------------
__global__ void k_hist(const int* __restrict__ ei, int* __restrict__ deg){
  int e = blockIdx.x*blockDim.x + threadIdx.x;
  if (e >= E_TOT) return;
  int s, d; edge_sd(ei, e, s, d);
  atomicAdd(&deg[d], 1);
}

__global__ void k_scan_a(const int* __restrict__ deg, int* __restrict__ rs,
                         int* __restrict__ bsum){
  __shared__ int sh[256];
  int i = blockIdx.x*256 + threadIdx.x;
  int v = (i < N_NODESC) ? deg[i] : 0;
  sh[threadIdx.x] = v;
  __syncthreads();
  for (int off=1; off<256; off<<=1){
    int t = (threadIdx.x >= off) ? sh[threadIdx.x-off] : 0;
    __syncthreads();
    sh[threadIdx.x] += t;
    __syncthreads();
  }
  if (i < N_NODESC) rs[i] = sh[threadIdx.x] - v;
  if (threadIdx.x == 255) bsum[blockIdx.x] = sh[255];
}

__global__ void k_scan_b(int* __restrict__ bsum){
  __shared__ int sh[256];
  int v = (threadIdx.x < NB_SCAN) ? bsum[threadIdx.x] : 0;
  sh[threadIdx.x] = v;
  __syncthreads();
  for (int off=1; off<256; off<<=1){
    int t = (threadIdx.x >= off) ? sh[threadIdx.x-off] : 0;
    __syncthreads();
    sh[threadIdx.x] += t;
    __syncthreads();
  }
  if (threadIdx.x < NB_SCAN) bsum[threadIdx.x] = sh[threadIdx.x] - v;
}

__global__ void k_scan_c(int* __restrict__ rs, const int* __restrict__ bsum,
                         int* __restrict__ cursor){
  int i = blockIdx.x*256 + threadIdx.x;
  if (i >= N_NODESC) return;
  int v = rs[i] + bsum[blockIdx.x];
  rs[i] = v;
  cursor[i] = v;
}

__global__ void k_fill(const int* __restrict__ ei, int* __restrict__ cursor,
                       int* __restrict__ csrc){
  int e = blockIdx.x*blockDim.x + threadIdx.x;
  if (e >= E_TOT) return;
  int s, d; edge_sd(ei, e, s, d);
  int pos = atomicAdd(&cursor[d], 1);
  csrc[pos] = s;
}

// ---------------- register-B MFMA GEMM (both outputs bf16 tables) ----------------
// Block = 4 waves. Waves 0,1 -> A@Wl into Olb; waves 2,3 -> A@Wr into Orb.
// Each wave owns NCW column-tiles of B in VGPRs; A (hi/lo bf16) double-buffered.
template<int NCW, int SPB>
__launch_bounds__(256, 2)
__global__ void k_gemm_regB(const u16* __restrict__ Ahi, const u16* __restrict__ Alo,
                            const u16* __restrict__ BlT, const u16* __restrict__ BrT,
                            u16* __restrict__ Olb, u16* __restrict__ Orb){
  constexpr int NLD = 2*NCW*16;
  int wave = threadIdx.x >> 6, lane = threadIdx.x & 63;
  int m = lane & 15, quad = lane >> 4;
  bool isl = (wave < 2);
  int ctbase = (isl ? wave : wave - 2) * NCW;
  const u16* __restrict__ BT = isl ? BlT : BrT;
  u16* __restrict__ Ob = isl ? Olb : Orb;

  short8 breg[NCW][4];
  #pragma unroll
  for (int c=0;c<NCW;c++)
    #pragma unroll
    for (int t=0;t<4;t++)
      breg[c][t] = *(const short8*)(BT + ((size_t)(((ctbase+c)*4 + t)*64) + lane)*8);

  int strip0 = blockIdx.x * SPB;
  short8 ah[2][4], al[2][4];

  {
    const u16* p1 = Ahi + (size_t)(strip0*16 + m)*128 + quad*8;
    const u16* p2 = Alo + (size_t)(strip0*16 + m)*128 + quad*8;
    #pragma unroll
    for (int t=0;t<4;t++){
      ah[0][t] = *(const short8*)(p1 + t*32);
      al[0][t] = *(const short8*)(p2 + t*32);
    }
  }

  #pragma unroll
  for (int i=0;i<SPB;i++){
    int s = strip0 + i;
    if (s >= N_STRIPS) break;
    if (i+1 < SPB && s+1 < N_STRIPS){
      const u16* p1 = Ahi + (size_t)((s+1)*16 + m)*128 + quad*8;
      const u16* p2 = Alo + (size_t)((s+1)*16 + m)*128 + quad*8;
      #pragma unroll
      for (int t=0;t<4;t++){
        ah[(i+1)&1][t] = *(const short8*)(p1 + t*32);
        al[(i+1)&1][t] = *(const short8*)(p2 + t*32);
      }
    }
    const int b = i&1;
    floatx4 acc[NCW];
    #pragma unroll
    for (int c=0;c<NCW;c++) acc[c] = (floatx4){0.f,0.f,0.f,0.f};
    #pragma unroll
    for (int t=0;t<4;t++){
      #pragma unroll
      for (int c=0;c<NCW;c++){
        acc[c] = __builtin_amdgcn_mfma_f32_16x16x32_bf16(ah[b][t], breg[c][t], acc[c], 0,0,0);
        acc[c] = __builtin_amdgcn_mfma_f32_16x16x32_bf16(al[b][t], breg[c][t], acc[c], 0,0,0);
      }
    }
    int row0 = s*16;
    #pragma unroll
    for (int c=0;c<NCW;c++)
      #pragma unroll
      for (int r=0;r<4;r++)
        Ob[(size_t)(row0 + quad*4 + r)*NLD + (ctbase+c)*16 + m] = f2bf(acc[c][r]);
  }
}

// ---------------- layer 1 fused: 4 groups x 16 lanes, one edge per group ----------
// Wave per dst (offset d0 for split dispatch). Lane l covers ch 8l..8l+7
// (head = l>>2). Per-head score reduced in 2 shfl; cross-group combine at end.
// No max-subtraction (scores O(5), exp safe; alpha shift-invariant). xr bf16.
__global__ void k_fused1(const int* __restrict__ rs, const int* __restrict__ deg,
                         const int* __restrict__ csrc, const u16* __restrict__ xlb,
                         const u16* __restrict__ xrb, const float* __restrict__ att,
                         const float* __restrict__ b1,
                         u16* __restrict__ Hhi, u16* __restrict__ Hlo, int d0){
  int wave = threadIdx.x >> 6;
  int lane = threadIdx.x & 63;
  int d = d0 + blockIdx.x*4 + wave;
  if (d >= N_NODESC) return;
  int g = lane >> 4;        // edge slot
  int l = lane & 15;        // channel slice: 8l..8l+7

  float xrv[8], atv[8];
  {
    ushort8v xq = *(const ushort8v*)(xrb + (size_t)d*HC + 8*l);
    #pragma unroll
    for (int j=0;j<8;j++) xrv[j] = bf2f(xq[j]);
    float4 c = *(const float4*)(att + 8*l);
    float4 e = *(const float4*)(att + 8*l + 4);
    atv[0]=c.x; atv[1]=c.y; atv[2]=c.z; atv[3]=c.w;
    atv[4]=e.x; atv[5]=e.y; atv[6]=e.z; atv[7]=e.w;
  }

  int start = rs[d], degd = deg[d];

  float acc[8];
  #pragma unroll
  for (int j=0;j<8;j++) acc[j] = 0.f;
  float den = 0.f;

  int s_cur = csrc[start + ((g < degd) ? g : 0)];
  for (int i = 0; i < degd; i += 4){
    bool valid = (i + g < degd);
    int s = s_cur;
    int en = i + 4 + g;
    s_cur = csrc[start + ((en < degd) ? en : 0)];   // prefetch next iter
    ushort8v q = *(const ushort8v*)(xlb + (size_t)s*HC + 8*l);  // 16B gather
    float xv[8];
    float sc = 0.f;
    #pragma unroll
    for (int j=0;j<8;j++){
      xv[j] = bf2f(q[j]);
      sc = fmaf(lrelu(xv[j] + xrv[j]), atv[j], sc);
    }
    sc += __shfl_xor(sc, 1);
    sc += __shfl_xor(sc, 2);          // per-head sum (4-lane span)
    float p = valid ? __expf(sc) : 0.f;
    den += p;
    #pragma unroll
    for (int j=0;j<8;j++) acc[j] = fmaf(p, xv[j], acc[j]);
  }
  // cross-group combine
  #pragma unroll
  for (int j=0;j<8;j++){
    acc[j] += __shfl_xor(acc[j], 16);
    acc[j] += __shfl_xor(acc[j], 32);
  }
  den += __shfl_xor(den, 16);
  den += __shfl_xor(den, 32);

  if (g == 0){
    float bv[8];
    float4 a = *(const float4*)(b1 + 8*l);
    float4 b = *(const float4*)(b1 + 8*l + 4);
    bv[0]=a.x; bv[1]=a.y; bv[2]=a.z; bv[3]=a.w;
    bv[4]=b.x; bv[5]=b.y; bv[6]=b.z; bv[7]=b.w;
    float inv = 1.f / (den + 1e-16f);
    u16 ohv[8], olv[8];
    #pragma unroll
    for (int j=0;j<8;j++){
      float o = acc[j]*inv + bv[j];
      o = (o > 0.f) ? o : (__expf(o) - 1.f);
      u16 h = f2bf(o);
      ohv[j] = h;
      olv[j] = f2bf(o - bf2f(h));
    }
    ushort4 h0 = {ohv[0],ohv[1],ohv[2],ohv[3]}, h1 = {ohv[4],ohv[5],ohv[6],ohv[7]};
    ushort4 l0 = {olv[0],olv[1],olv[2],olv[3]}, l1 = {olv[4],olv[5],olv[6],olv[7]};
    *(ushort4*)(Hhi + (size_t)d*HC + 8*l)     = h0;
    *(ushort4*)(Hhi + (size_t)d*HC + 8*l + 4) = h1;
    *(ushort4*)(Hlo + (size_t)d*HC + 8*l)     = l0;
    *(ushort4*)(Hlo + (size_t)d*HC + 8*l + 4) = l1;
  }
}

// ---------------- layer 2 fused: 4 groups x 16 lanes, one edge per group ----------
// Lane l covers ch 4l..4l+3 (8B gather); score over 16 lanes (4 shfl); heads=1.
__global__ void k_fused2(const int* __restrict__ rs, const int* __restrict__ deg,
                         const int* __restrict__ csrc, const u16* __restrict__ xlb,
                         const u16* __restrict__ xrb, const float* __restrict__ att,
                         const float* __restrict__ b2, float* __restrict__ out){
  int wave = threadIdx.x >> 6;
  int lane = threadIdx.x & 63;
  int d = blockIdx.x*4 + wave;
  if (d >= N_NODESC) return;
  int g = lane >> 4;
  int l = lane & 15;        // channels 4l..4l+3

  float xrv[4], atv[4];
  {
    ushort4v xq = *(const ushort4v*)(xrb + (size_t)d*OUT_CH + 4*l);
    #pragma unroll
    for (int j=0;j<4;j++) xrv[j] = bf2f(xq[j]);
    float4 c = *(const float4*)(att + 4*l);
    atv[0]=c.x; atv[1]=c.y; atv[2]=c.z; atv[3]=c.w;
  }

  int start = rs[d], degd = deg[d];

  float acc[4] = {0.f,0.f,0.f,0.f};
  float den = 0.f;

  int s_cur = csrc[start + ((g < degd) ? g : 0)];
  for (int i = 0; i < degd; i += 4){
    bool valid = (i + g < degd);
    int s = s_cur;
    int en = i + 4 + g;
    s_cur = csrc[start + ((en < degd) ? en : 0)];
    uint2 q = *(const uint2*)(xlb + (size_t)s*OUT_CH + 4*l);   // 8B gather
    float xv[4];
    xv[0]=bflo(q.x); xv[1]=bfhi(q.x);
    xv[2]=bflo(q.y); xv[3]=bfhi(q.y);
    float sc = 0.f;
    #pragma unroll
    for (int j=0;j<4;j++) sc = fmaf(lrelu(xv[j] + xrv[j]), atv[j], sc);
    sc += __shfl_xor(sc, 1);
    sc += __shfl_xor(sc, 2);
    sc += __shfl_xor(sc, 4);
    sc += __shfl_xor(sc, 8);          // full 64-ch sum
    float p = valid ? __expf(sc) : 0.f;
    den += p;
    #pragma unroll
    for (int j=0;j<4;j++) acc[j] = fmaf(p, xv[j], acc[j]);
  }
  #pragma unroll
  for (int j=0;j<4;j++){
    acc[j] += __shfl_xor(acc[j], 16);
    acc[j] += __shfl_xor(acc[j], 32);
  }
  den += __shfl_xor(den, 16);
  den += __shfl_xor(den, 32);

  if (g == 0){
    float4 bvv = *(const float4*)(b2 + 4*l);
    float inv = 1.f / (den + 1e-16f);
    float4 o;
    o.x = acc[0]*inv + bvv.x;
    o.y = acc[1]*inv + bvv.y;
    o.z = acc[2]*inv + bvv.z;
    o.w = acc[3]*inv + bvv.w;
    *(float4*)(out + (size_t)d*OUT_CH + 4*l) = o;
  }
}

extern "C" void kernel_launch(void* const* d_in, const int* in_sizes, int n_in,
                              void* d_out, int out_size, void* d_ws, size_t ws_size,
                              hipStream_t stream) {
  const float* x    = (const float*)d_in[0];
  const int*   ei   = (const int*)d_in[1];
  const float* W1l  = (const float*)d_in[2];
  const float* W1r  = (const float*)d_in[3];
  const float* att1 = (const float*)d_in[4];
  const float* b1   = (const float*)d_in[5];
  const float* W2l  = (const float*)d_in[6];
  const float* W2r  = (const float*)d_in[7];
  const float* att2 = (const float*)d_in[8];
  const float* b2   = (const float*)d_in[9];
  float* out = (float*)d_out;

  // workspace layout (units of float; offsets multiples of 4 -> 16B aligned)
  float* ws = (float*)d_ws;
  size_t off = 0;
  u16* xl1b = (u16*)(ws + off); off += (size_t)N_NODESC*HC/2;     // bf16 [N x 128]
  u16* xr1b = (u16*)(ws + off); off += (size_t)N_NODESC*HC/2;
  u16* xl2b = (u16*)(ws + off); off += (size_t)N_NODESC*OUT_CH/2; // bf16 [N x 64]
  u16* xr2b = (u16*)(ws + off); off += (size_t)N_NODESC*OUT_CH/2;
  u16* xhi = (u16*)(ws + off); off += (size_t)N_NODESC*HC/2;      // A for gemm1
  u16* xlo = (u16*)(ws + off); off += (size_t)N_NODESC*HC/2;
  u16* hhi = (u16*)(ws + off); off += (size_t)N_NODESC*HC/2;      // A for gemm2
  u16* hlo = (u16*)(ws + off); off += (size_t)N_NODESC*HC/2;
  u16* w1lh = (u16*)(ws + off); off += IN_CH*HC/2;
  u16* w1rh = (u16*)(ws + off); off += IN_CH*HC/2;
  u16* w2lh = (u16*)(ws + off); off += HC*OUT_CH/2;
  u16* w2rh = (u16*)(ws + off); off += HC*OUT_CH/2;
  int* deg    = (int*)(ws + off); off += N_NODESC;
  int* rs     = (int*)(ws + off); off += N_NODESC;
  int* cursor = (int*)(ws + off); off += N_NODESC;
  int* bsum   = (int*)(ws + off); off += 256;
  int* csrc   = (int*)(ws + off); off += E_TOT;

  // ---- misc (zero deg + weight prep + x split), then CSR build ----
  k_misc<<<220 + (N_NODESC*HC/4 + 255)/256, 256, 0, stream>>>(
      deg, x, xhi, xlo, W1l, W1r, W2l, W2r, w1lh, w1rh, w2lh, w2rh);
  k_hist<<<(E_TOT+255)/256, 256, 0, stream>>>(ei, deg);
  k_scan_a<<<NB_SCAN, 256, 0, stream>>>(deg, rs, bsum);
  k_scan_b<<<1, 256, 0, stream>>>(bsum);
  k_scan_c<<<NB_SCAN, 256, 0, stream>>>(rs, bsum, cursor);
  k_fill<<<(E_TOT+255)/256, 256, 0, stream>>>(ei, cursor, csrc);

  const int NB_G = (N_STRIPS + 3)/4;   // SPB=4
  // ---- layer 1 ----
  k_gemm_regB<4,4><<<NB_G, 256, 0, stream>>>(xhi, xlo, w1lh, w1rh, xl1b, xr1b);
  // split into two half-grids: equal work, and un-hides the #2 kernel in top-5
  k_fused1<<<(N_NODESC/2+3)/4, 256, 0, stream>>>(rs, deg, csrc, xl1b, xr1b, att1, b1, hhi, hlo, 0);
  k_fused1<<<(N_NODESC/2+3)/4, 256, 0, stream>>>(rs, deg, csrc, xl1b, xr1b, att1, b1, hhi, hlo, N_NODESC/2);

  // ---- layer 2 ----
  k_gemm_regB<2,4><<<NB_G, 256, 0, stream>>>(hhi, hlo, w2lh, w2rh, xl2b, xr2b);
  k_fused2<<<(N_NODESC+3)/4, 256, 0, stream>>>(rs, deg, csrc, xl2b, xr2b, att2, b2, out);
}

// Round 10
// 250.130 us; speedup vs baseline: 1.0713x; 1.0590x over previous
//
#include <hip/hip_runtime.h>
#include <hip/hip_bf16.h>
#include <math.h>

#define N_NODESC 50000
#define N_EDGESC 500000
#define E_TOT    (N_EDGESC + N_NODESC)   // 550000 (self-loops appended)
#define IN_CH 128
#define HID 32
#define HEADS 4
#define HC (HEADS*HID)    // 128
#define OUT_CH 64
#define NEG_SLOPE 0.2f
#define NB_SCAN 196        // ceil(50000/256)
#define N_STRIPS (N_NODESC/16)   // 3125 exact
#define NB_HIST 2149       // ceil(E_TOT/256)
#define NB_PREP 24
#define NB_SPLIT 6250      // ceil(N_NODESC*HC/4/256)

typedef unsigned short u16;
typedef __attribute__((ext_vector_type(8))) short short8;          // 8 bf16 (4 VGPRs)
typedef __attribute__((ext_vector_type(8))) unsigned short ushort8v;
typedef __attribute__((ext_vector_type(4))) float floatx4;         // 4 fp32 acc

// manual bf16 round-to-nearest-even
__device__ __forceinline__ u16 f2bf(float f){
  unsigned u = __float_as_uint(f);
  return (u16)((u + 0x7FFFu + ((u >> 16) & 1u)) >> 16);
}
__device__ __forceinline__ float bf2f(u16 b){ return __uint_as_float(((unsigned)b) << 16); }
// lrelu(v) = max(v, 0.2v)  (valid since 0 < slope < 1)
__device__ __forceinline__ float lrelu(float v){ return fmaxf(v, NEG_SLOPE*v); }

__device__ __forceinline__ void edge_sd(const int* __restrict__ ei, int e, int& s, int& d){
  if (e < N_EDGESC){ s = ei[e]; d = ei[N_EDGESC + e]; }
  else { s = e - N_EDGESC; d = s; }
}

// ---------------- misc: hist + weight prep + x split (deg pre-zeroed by memset) ----
// blocks 0..2148: hist; 2149..2172: weight prep; 2173..: x hi/lo split.
__global__ void k_misc(const int* __restrict__ ei, int* __restrict__ deg,
                       const float* __restrict__ X, u16* __restrict__ xhi, u16* __restrict__ xlo,
                       const float* __restrict__ W1l, const float* __restrict__ W1r,
                       const float* __restrict__ W2l, const float* __restrict__ W2r,
                       u16* __restrict__ w1lh, u16* __restrict__ w1rh,
                       u16* __restrict__ w2lh, u16* __restrict__ w2rh){
  int b = blockIdx.x;
  if (b < NB_HIST){
    int e = b*256 + threadIdx.x;
    if (e < E_TOT){
      int s, d; edge_sd(ei, e, s, d);
      atomicAdd(&deg[d], 1);
    }
  } else if (b < NB_HIST + NB_PREP){
    int bb = b - NB_HIST;
    const float* W; u16 *Th; int N, base;
    if (bb < 8)      { W=W1l; Th=w1lh; N=HC;     base=bb;    }
    else if (bb < 16){ W=W1r; Th=w1rh; N=HC;     base=bb-8;  }
    else if (bb < 20){ W=W2l; Th=w2lh; N=OUT_CH; base=bb-16; }
    else             { W=W2r; Th=w2rh; N=OUT_CH; base=bb-20; }
    // packed idx = (((c*4 + t)*64) + lane)*8 + j
    // value      = W[(t*32 + (lane>>4)*8 + j)*N + c*16 + (lane&15)]
    int tid = base*256 + threadIdx.x;
    int lane = tid & 63;
    int t = (tid >> 6) & 3;
    int c = tid >> 8;
    int k0 = t*32 + (lane>>4)*8;
    int n  = c*16 + (lane&15);
    #pragma unroll
    for (int j=0;j<8;j++){
      Th[(size_t)tid*8 + j] = f2bf(W[(size_t)(k0+j)*N + n]);
    }
  } else {
    int i = (b - NB_HIST - NB_PREP)*256 + threadIdx.x;
    if (i < N_NODESC*HC/4){
      float4 v = ((const float4*)X)[i];
      ushort4 h, l;
      h.x = f2bf(v.x); l.x = f2bf(v.x - bf2f(h.x));
      h.y = f2bf(v.y); l.y = f2bf(v.y - bf2f(h.y));
      h.z = f2bf(v.z); l.z = f2bf(v.z - bf2f(h.z));
      h.w = f2bf(v.w); l.w = f2bf(v.w - bf2f(h.w));
      ((ushort4*)xhi)[i] = h;
      ((ushort4*)xlo)[i] = l;
    }
  }
}

// ---------------- CSR scan ----------------
__global__ void k_scan_a(const int* __restrict__ deg, int* __restrict__ rs,
                         int* __restrict__ bsum){
  __shared__ int sh[256];
  int i = blockIdx.x*256 + threadIdx.x;
  int v = (i < N_NODESC) ? deg[i] : 0;
  sh[threadIdx.x] = v;
  __syncthreads();
  for (int off=1; off<256; off<<=1){
    int t = (threadIdx.x >= off) ? sh[threadIdx.x-off] : 0;
    __syncthreads();
    sh[threadIdx.x] += t;
    __syncthreads();
  }
  if (i < N_NODESC) rs[i] = sh[threadIdx.x] - v;       // exclusive within block
  if (threadIdx.x == 255) bsum[blockIdx.x] = sh[255];  // block total
}

// scan of bsum (redone per block, cheap) + add + cursor init, one kernel
__global__ void k_scan_bc(int* __restrict__ rs, const int* __restrict__ bsum,
                          int* __restrict__ cursor){
  __shared__ int sh[256];
  int v = (threadIdx.x < NB_SCAN) ? bsum[threadIdx.x] : 0;
  sh[threadIdx.x] = v;
  __syncthreads();
  for (int off=1; off<256; off<<=1){
    int t = (threadIdx.x >= off) ? sh[threadIdx.x-off] : 0;
    __syncthreads();
    sh[threadIdx.x] += t;
    __syncthreads();
  }
  // exclusive prefix for this block = inclusive[blockIdx.x] - bsum[blockIdx.x]
  int add = sh[blockIdx.x] - bsum[blockIdx.x];
  int i = blockIdx.x*256 + threadIdx.x;
  if (i < N_NODESC){
    int v2 = rs[i] + add;
    rs[i] = v2;
    cursor[i] = v2;
  }
}

__global__ void k_fill(const int* __restrict__ ei, int* __restrict__ cursor,
                       int* __restrict__ csrc){
  int e = blockIdx.x*blockDim.x + threadIdx.x;
  if (e >= E_TOT) return;
  int s, d; edge_sd(ei, e, s, d);
  int pos = atomicAdd(&cursor[d], 1);
  csrc[pos] = s;
}

// ---------------- register-B MFMA GEMM (both outputs bf16 tables) ----------------
// Block = 4 waves. Waves 0,1 -> A@Wl into Olb; waves 2,3 -> A@Wr into Orb.
// Each wave owns NCW column-tiles of B in VGPRs; A (hi/lo bf16) double-buffered.
template<int NCW, int SPB>
__launch_bounds__(256, 2)
__global__ void k_gemm_regB(const u16* __restrict__ Ahi, const u16* __restrict__ Alo,
                            const u16* __restrict__ BlT, const u16* __restrict__ BrT,
                            u16* __restrict__ Olb, u16* __restrict__ Orb){
  constexpr int NLD = 2*NCW*16;
  int wave = threadIdx.x >> 6, lane = threadIdx.x & 63;
  int m = lane & 15, quad = lane >> 4;
  bool isl = (wave < 2);
  int ctbase = (isl ? wave : wave - 2) * NCW;
  const u16* __restrict__ BT = isl ? BlT : BrT;
  u16* __restrict__ Ob = isl ? Olb : Orb;

  short8 breg[NCW][4];
  #pragma unroll
  for (int c=0;c<NCW;c++)
    #pragma unroll
    for (int t=0;t<4;t++)
      breg[c][t] = *(const short8*)(BT + ((size_t)(((ctbase+c)*4 + t)*64) + lane)*8);

  int strip0 = blockIdx.x * SPB;
  short8 ah[2][4], al[2][4];

  {
    const u16* p1 = Ahi + (size_t)(strip0*16 + m)*128 + quad*8;
    const u16* p2 = Alo + (size_t)(strip0*16 + m)*128 + quad*8;
    #pragma unroll
    for (int t=0;t<4;t++){
      ah[0][t] = *(const short8*)(p1 + t*32);
      al[0][t] = *(const short8*)(p2 + t*32);
    }
  }

  #pragma unroll
  for (int i=0;i<SPB;i++){
    int s = strip0 + i;
    if (s >= N_STRIPS) break;
    if (i+1 < SPB && s+1 < N_STRIPS){
      const u16* p1 = Ahi + (size_t)((s+1)*16 + m)*128 + quad*8;
      const u16* p2 = Alo + (size_t)((s+1)*16 + m)*128 + quad*8;
      #pragma unroll
      for (int t=0;t<4;t++){
        ah[(i+1)&1][t] = *(const short8*)(p1 + t*32);
        al[(i+1)&1][t] = *(const short8*)(p2 + t*32);
      }
    }
    const int b = i&1;
    floatx4 acc[NCW];
    #pragma unroll
    for (int c=0;c<NCW;c++) acc[c] = (floatx4){0.f,0.f,0.f,0.f};
    #pragma unroll
    for (int t=0;t<4;t++){
      #pragma unroll
      for (int c=0;c<NCW;c++){
        acc[c] = __builtin_amdgcn_mfma_f32_16x16x32_bf16(ah[b][t], breg[c][t], acc[c], 0,0,0);
        acc[c] = __builtin_amdgcn_mfma_f32_16x16x32_bf16(al[b][t], breg[c][t], acc[c], 0,0,0);
      }
    }
    int row0 = s*16;
    #pragma unroll
    for (int c=0;c<NCW;c++)
      #pragma unroll
      for (int r=0;r<4;r++)
        Ob[(size_t)(row0 + quad*4 + r)*NLD + (ctbase+c)*16 + m] = f2bf(acc[c][r]);
  }
}

// ---------------- layer 1 fused: 4 groups x 16 lanes, one edge per group ----------
// Wave per dst. Lane l covers ch 8l..8l+7 (head = l>>2). Per-head score reduced
// in 2 shfl; cross-group combine at end. No max-subtraction (scores O(5), exp
// safe; alpha shift-invariant). xl/xr tables bf16.
__global__ void k_fused1(const int* __restrict__ rs, const int* __restrict__ deg,
                         const int* __restrict__ csrc, const u16* __restrict__ xlb,
                         const u16* __restrict__ xrb, const float* __restrict__ att,
                         const float* __restrict__ b1,
                         u16* __restrict__ Hhi, u16* __restrict__ Hlo){
  int wave = threadIdx.x >> 6;
  int lane = threadIdx.x & 63;
  int d = blockIdx.x*4 + wave;
  if (d >= N_NODESC) return;
  int g = lane >> 4;        // edge slot
  int l = lane & 15;        // channel slice: 8l..8l+7

  float xrv[8], atv[8];
  {
    ushort8v xq = *(const ushort8v*)(xrb + (size_t)d*HC + 8*l);
    #pragma unroll
    for (int j=0;j<8;j++) xrv[j] = bf2f(xq[j]);
    float4 c = *(const float4*)(att + 8*l);
    float4 e = *(const float4*)(att + 8*l + 4);
    atv[0]=c.x; atv[1]=c.y; atv[2]=c.z; atv[3]=c.w;
    atv[4]=e.x; atv[5]=e.y; atv[6]=e.z; atv[7]=e.w;
  }

  int start = rs[d], degd = deg[d];

  float acc[8];
  #pragma unroll
  for (int j=0;j<8;j++) acc[j] = 0.f;
  float den = 0.f;

  int s_cur = csrc[start + ((g < degd) ? g : 0)];
  for (int i = 0; i < degd; i += 4){
    bool valid = (i + g < degd);
    int s = s_cur;
    int en = i + 4 + g;
    s_cur = csrc[start + ((en < degd) ? en : 0)];   // prefetch next iter
    ushort8v q = *(const ushort8v*)(xlb + (size_t)s*HC + 8*l);  // 16B gather
    float xv[8];
    float sc = 0.f;
    #pragma unroll
    for (int j=0;j<8;j++){
      xv[j] = bf2f(q[j]);
      sc = fmaf(lrelu(xv[j] + xrv[j]), atv[j], sc);
    }
    sc += __shfl_xor(sc, 1);
    sc += __shfl_xor(sc, 2);          // per-head sum (4-lane span)
    float p = valid ? __expf(sc) : 0.f;
    den += p;
    #pragma unroll
    for (int j=0;j<8;j++) acc[j] = fmaf(p, xv[j], acc[j]);
  }
  // cross-group combine
  #pragma unroll
  for (int j=0;j<8;j++){
    acc[j] += __shfl_xor(acc[j], 16);
    acc[j] += __shfl_xor(acc[j], 32);
  }
  den += __shfl_xor(den, 16);
  den += __shfl_xor(den, 32);

  if (g == 0){
    float bv[8];
    float4 a = *(const float4*)(b1 + 8*l);
    float4 b = *(const float4*)(b1 + 8*l + 4);
    bv[0]=a.x; bv[1]=a.y; bv[2]=a.z; bv[3]=a.w;
    bv[4]=b.x; bv[5]=b.y; bv[6]=b.z; bv[7]=b.w;
    float inv = 1.f / (den + 1e-16f);
    u16 ohv[8], olv[8];
    #pragma unroll
    for (int j=0;j<8;j++){
      float o = acc[j]*inv + bv[j];
      o = (o > 0.f) ? o : (__expf(o) - 1.f);
      u16 h = f2bf(o);
      ohv[j] = h;
      olv[j] = f2bf(o - bf2f(h));
    }
    ushort4 h0 = {ohv[0],ohv[1],ohv[2],ohv[3]}, h1 = {ohv[4],ohv[5],ohv[6],ohv[7]};
    ushort4 l0 = {olv[0],olv[1],olv[2],olv[3]}, l1 = {olv[4],olv[5],olv[6],olv[7]};
    *(ushort4*)(Hhi + (size_t)d*HC + 8*l)     = h0;
    *(ushort4*)(Hhi + (size_t)d*HC + 8*l + 4) = h1;
    *(ushort4*)(Hlo + (size_t)d*HC + 8*l)     = l0;
    *(ushort4*)(Hlo + (size_t)d*HC + 8*l + 4) = l1;
  }
}

// ---------------- layer 2 fused: 8 groups x 8 lanes, one edge per group ----------
// Lane l covers ch 8l..8l+7 (16B gather); score over 8 lanes (3 shfl); heads=1;
// serial iterations per dst = ceil(deg/8).
__global__ void k_fused2(const int* __restrict__ rs, const int* __restrict__ deg,
                         const int* __restrict__ csrc, const u16* __restrict__ xlb,
                         const u16* __restrict__ xrb, const float* __restrict__ att,
                         const float* __restrict__ b2, float* __restrict__ out){
  int wave = threadIdx.x >> 6;
  int lane = threadIdx.x & 63;
  int d = blockIdx.x*4 + wave;
  if (d >= N_NODESC) return;
  int g = lane >> 3;        // 8 edge slots
  int l = lane & 7;         // channels 8l..8l+7

  float xrv[8], atv[8];
  {
    ushort8v xq = *(const ushort8v*)(xrb + (size_t)d*OUT_CH + 8*l);
    #pragma unroll
    for (int j=0;j<8;j++) xrv[j] = bf2f(xq[j]);
    float4 c = *(const float4*)(att + 8*l);
    float4 e = *(const float4*)(att + 8*l + 4);
    atv[0]=c.x; atv[1]=c.y; atv[2]=c.z; atv[3]=c.w;
    atv[4]=e.x; atv[5]=e.y; atv[6]=e.z; atv[7]=e.w;
  }

  int start = rs[d], degd = deg[d];

  float acc[8];
  #pragma unroll
  for (int j=0;j<8;j++) acc[j] = 0.f;
  float den = 0.f;

  int s_cur = csrc[start + ((g < degd) ? g : 0)];
  for (int i = 0; i < degd; i += 8){
    bool valid = (i + g < degd);
    int s = s_cur;
    int en = i + 8 + g;
    s_cur = csrc[start + ((en < degd) ? en : 0)];   // prefetch next iter
    ushort8v q = *(const ushort8v*)(xlb + (size_t)s*OUT_CH + 8*l);  // 16B gather
    float xv[8];
    float sc = 0.f;
    #pragma unroll
    for (int j=0;j<8;j++){
      xv[j] = bf2f(q[j]);
      sc = fmaf(lrelu(xv[j] + xrv[j]), atv[j], sc);
    }
    sc += __shfl_xor(sc, 1);
    sc += __shfl_xor(sc, 2);
    sc += __shfl_xor(sc, 4);          // full 64-ch sum (8-lane span)
    float p = valid ? __expf(sc) : 0.f;
    den += p;
    #pragma unroll
    for (int j=0;j<8;j++) acc[j] = fmaf(p, xv[j], acc[j]);
  }
  // cross-group combine (8 groups)
  #pragma unroll
  for (int j=0;j<8;j++){
    acc[j] += __shfl_xor(acc[j], 8);
    acc[j] += __shfl_xor(acc[j], 16);
    acc[j] += __shfl_xor(acc[j], 32);
  }
  den += __shfl_xor(den, 8);
  den += __shfl_xor(den, 16);
  den += __shfl_xor(den, 32);

  if (g == 0){
    float bv[8];
    float4 a = *(const float4*)(b2 + 8*l);
    float4 b = *(const float4*)(b2 + 8*l + 4);
    bv[0]=a.x; bv[1]=a.y; bv[2]=a.z; bv[3]=a.w;
    bv[4]=b.x; bv[5]=b.y; bv[6]=b.z; bv[7]=b.w;
    float inv = 1.f / (den + 1e-16f);
    float4 o0, o1;
    o0.x = acc[0]*inv + bv[0]; o0.y = acc[1]*inv + bv[1];
    o0.z = acc[2]*inv + bv[2]; o0.w = acc[3]*inv + bv[3];
    o1.x = acc[4]*inv + bv[4]; o1.y = acc[5]*inv + bv[5];
    o1.z = acc[6]*inv + bv[6]; o1.w = acc[7]*inv + bv[7];
    *(float4*)(out + (size_t)d*OUT_CH + 8*l)     = o0;
    *(float4*)(out + (size_t)d*OUT_CH + 8*l + 4) = o1;
  }
}

extern "C" void kernel_launch(void* const* d_in, const int* in_sizes, int n_in,
                              void* d_out, int out_size, void* d_ws, size_t ws_size,
                              hipStream_t stream) {
  const float* x    = (const float*)d_in[0];
  const int*   ei   = (const int*)d_in[1];
  const float* W1l  = (const float*)d_in[2];
  const float* W1r  = (const float*)d_in[3];
  const float* att1 = (const float*)d_in[4];
  const float* b1   = (const float*)d_in[5];
  const float* W2l  = (const float*)d_in[6];
  const float* W2r  = (const float*)d_in[7];
  const float* att2 = (const float*)d_in[8];
  const float* b2   = (const float*)d_in[9];
  float* out = (float*)d_out;

  // workspace layout (units of float; offsets multiples of 4 -> 16B aligned)
  float* ws = (float*)d_ws;
  size_t off = 0;
  u16* xl1b = (u16*)(ws + off); off += (size_t)N_NODESC*HC/2;     // bf16 [N x 128]
  u16* xr1b = (u16*)(ws + off); off += (size_t)N_NODESC*HC/2;
  u16* xl2b = (u16*)(ws + off); off += (size_t)N_NODESC*OUT_CH/2; // bf16 [N x 64]
  u16* xr2b = (u16*)(ws + off); off += (size_t)N_NODESC*OUT_CH/2;
  u16* xhi = (u16*)(ws + off); off += (size_t)N_NODESC*HC/2;      // A for gemm1
  u16* xlo = (u16*)(ws + off); off += (size_t)N_NODESC*HC/2;
  u16* hhi = (u16*)(ws + off); off += (size_t)N_NODESC*HC/2;      // A for gemm2
  u16* hlo = (u16*)(ws + off); off += (size_t)N_NODESC*HC/2;
  u16* w1lh = (u16*)(ws + off); off += IN_CH*HC/2;
  u16* w1rh = (u16*)(ws + off); off += IN_CH*HC/2;
  u16* w2lh = (u16*)(ws + off); off += HC*OUT_CH/2;
  u16* w2rh = (u16*)(ws + off); off += HC*OUT_CH/2;
  int* deg    = (int*)(ws + off); off += N_NODESC;
  int* rs     = (int*)(ws + off); off += N_NODESC;
  int* cursor = (int*)(ws + off); off += N_NODESC;
  int* bsum   = (int*)(ws + off); off += 256;
  int* csrc   = (int*)(ws + off); off += E_TOT;

  // ---- zero deg (async memset) + misc (hist + prep + split) + CSR scan/fill ----
  hipMemsetAsync(deg, 0, N_NODESC*sizeof(int), stream);
  k_misc<<<NB_HIST + NB_PREP + NB_SPLIT, 256, 0, stream>>>(
      ei, deg, x, xhi, xlo, W1l, W1r, W2l, W2r, w1lh, w1rh, w2lh, w2rh);
  k_scan_a<<<NB_SCAN, 256, 0, stream>>>(deg, rs, bsum);
  k_scan_bc<<<NB_SCAN, 256, 0, stream>>>(rs, bsum, cursor);
  k_fill<<<(E_TOT+255)/256, 256, 0, stream>>>(ei, cursor, csrc);

  const int NB_G = (N_STRIPS + 3)/4;   // SPB=4
  // ---- layer 1 ----
  k_gemm_regB<4,4><<<NB_G, 256, 0, stream>>>(xhi, xlo, w1lh, w1rh, xl1b, xr1b);
  k_fused1<<<(N_NODESC+3)/4, 256, 0, stream>>>(rs, deg, csrc, xl1b, xr1b, att1, b1, hhi, hlo);

  // ---- layer 2 ----
  k_gemm_regB<2,4><<<NB_G, 256, 0, stream>>>(hhi, hlo, w2lh, w2rh, xl2b, xr2b);
  k_fused2<<<(N_NODESC+3)/4, 256, 0, stream>>>(rs, deg, csrc, xl2b, xr2b, att2, b2, out);
}

// Round 11
// 229.531 us; speedup vs baseline: 1.1674x; 1.0897x over previous
//
#include <hip/hip_runtime.h>
#include <hip/hip_bf16.h>
#include <math.h>

#define N_NODESC 50000
#define N_EDGESC 500000
#define E_TOT    (N_EDGESC + N_NODESC)   // 550000 (self-loops appended)
#define IN_CH 128
#define HID 32
#define HEADS 4
#define HC (HEADS*HID)    // 128
#define OUT_CH 64
#define NEG_SLOPE 0.2f
#define NB_SCAN 196        // ceil(50000/256)
#define N_STRIPS (N_NODESC/16)   // 3125 exact
#define NB_HIST 2149       // ceil(E_TOT/256)
#define NB_PREP 24
#define NB_SPLIT 6250      // ceil(N_NODESC*HC/4/256)

typedef unsigned short u16;
typedef __attribute__((ext_vector_type(8))) short short8;          // 8 bf16 (4 VGPRs)
typedef __attribute__((ext_vector_type(8))) unsigned short ushort8v;
typedef __attribute__((ext_vector_type(4))) float floatx4;         // 4 fp32 acc

// manual bf16 round-to-nearest-even
__device__ __forceinline__ u16 f2bf(float f){
  unsigned u = __float_as_uint(f);
  return (u16)((u + 0x7FFFu + ((u >> 16) & 1u)) >> 16);
}
__device__ __forceinline__ float bf2f(u16 b){ return __uint_as_float(((unsigned)b) << 16); }
// lrelu(v) = max(v, 0.2v)  (valid since 0 < slope < 1)
__device__ __forceinline__ float lrelu(float v){ return fmaxf(v, NEG_SLOPE*v); }

__device__ __forceinline__ void edge_sd(const int* __restrict__ ei, int e, int& s, int& d){
  if (e < N_EDGESC){ s = ei[e]; d = ei[N_EDGESC + e]; }
  else { s = e - N_EDGESC; d = s; }
}

// ---------------- misc: hist + weight prep + x->bf16 (deg pre-zeroed by memset) ----
// blocks 0..2148: hist; 2149..2172: weight prep; 2173..: x bf16 cast.
__global__ void k_misc(const int* __restrict__ ei, int* __restrict__ deg,
                       const float* __restrict__ X, u16* __restrict__ xhb,
                       const float* __restrict__ W1l, const float* __restrict__ W1r,
                       const float* __restrict__ W2l, const float* __restrict__ W2r,
                       u16* __restrict__ w1lh, u16* __restrict__ w1rh,
                       u16* __restrict__ w2lh, u16* __restrict__ w2rh){
  int b = blockIdx.x;
  if (b < NB_HIST){
    int e = b*256 + threadIdx.x;
    if (e < E_TOT){
      int s, d; edge_sd(ei, e, s, d);
      atomicAdd(&deg[d], 1);
    }
  } else if (b < NB_HIST + NB_PREP){
    int bb = b - NB_HIST;
    const float* W; u16 *Th; int N, base;
    if (bb < 8)      { W=W1l; Th=w1lh; N=HC;     base=bb;    }
    else if (bb < 16){ W=W1r; Th=w1rh; N=HC;     base=bb-8;  }
    else if (bb < 20){ W=W2l; Th=w2lh; N=OUT_CH; base=bb-16; }
    else             { W=W2r; Th=w2rh; N=OUT_CH; base=bb-20; }
    // packed idx = (((c*4 + t)*64) + lane)*8 + j
    // value      = W[(t*32 + (lane>>4)*8 + j)*N + c*16 + (lane&15)]
    int tid = base*256 + threadIdx.x;
    int lane = tid & 63;
    int t = (tid >> 6) & 3;
    int c = tid >> 8;
    int k0 = t*32 + (lane>>4)*8;
    int n  = c*16 + (lane&15);
    #pragma unroll
    for (int j=0;j<8;j++){
      Th[(size_t)tid*8 + j] = f2bf(W[(size_t)(k0+j)*N + n]);
    }
  } else {
    int i = (b - NB_HIST - NB_PREP)*256 + threadIdx.x;
    if (i < N_NODESC*HC/4){
      float4 v = ((const float4*)X)[i];
      ushort4 h;
      h.x = f2bf(v.x); h.y = f2bf(v.y); h.z = f2bf(v.z); h.w = f2bf(v.w);
      ((ushort4*)xhb)[i] = h;
    }
  }
}

// ---------------- CSR scan ----------------
__global__ void k_scan_a(const int* __restrict__ deg, int* __restrict__ rs,
                         int* __restrict__ bsum){
  __shared__ int sh[256];
  int i = blockIdx.x*256 + threadIdx.x;
  int v = (i < N_NODESC) ? deg[i] : 0;
  sh[threadIdx.x] = v;
  __syncthreads();
  for (int off=1; off<256; off<<=1){
    int t = (threadIdx.x >= off) ? sh[threadIdx.x-off] : 0;
    __syncthreads();
    sh[threadIdx.x] += t;
    __syncthreads();
  }
  if (i < N_NODESC) rs[i] = sh[threadIdx.x] - v;       // exclusive within block
  if (threadIdx.x == 255) bsum[blockIdx.x] = sh[255];  // block total
}

// scan of bsum (redone per block, cheap) + add + cursor init
__global__ void k_scan_bc(int* __restrict__ rs, const int* __restrict__ bsum,
                          int* __restrict__ cursor){
  __shared__ int sh[256];
  int v = (threadIdx.x < NB_SCAN) ? bsum[threadIdx.x] : 0;
  sh[threadIdx.x] = v;
  __syncthreads();
  for (int off=1; off<256; off<<=1){
    int t = (threadIdx.x >= off) ? sh[threadIdx.x-off] : 0;
    __syncthreads();
    sh[threadIdx.x] += t;
    __syncthreads();
  }
  int add = sh[blockIdx.x] - bsum[blockIdx.x];
  int i = blockIdx.x*256 + threadIdx.x;
  if (i < N_NODESC){
    int v2 = rs[i] + add;
    rs[i] = v2;
    cursor[i] = v2;
  }
}

__global__ void k_fill(const int* __restrict__ ei, int* __restrict__ cursor,
                       int* __restrict__ csrc){
  int e = blockIdx.x*blockDim.x + threadIdx.x;
  if (e >= E_TOT) return;
  int s, d; edge_sd(ei, e, s, d);
  int pos = atomicAdd(&cursor[d], 1);
  csrc[pos] = s;
}

// ---------------- register-B MFMA GEMM (bf16 A, bf16 B, bf16 outputs) -------------
// Block = 4 waves. Waves 0,1 -> A@Wl into Olb; waves 2,3 -> A@Wr into Orb.
// Each wave owns NCW column-tiles of B in VGPRs; A double-buffered in registers.
template<int NCW, int SPB>
__launch_bounds__(256, 2)
__global__ void k_gemm_regB(const u16* __restrict__ Ab,
                            const u16* __restrict__ BlT, const u16* __restrict__ BrT,
                            u16* __restrict__ Olb, u16* __restrict__ Orb){
  constexpr int NLD = 2*NCW*16;
  int wave = threadIdx.x >> 6, lane = threadIdx.x & 63;
  int m = lane & 15, quad = lane >> 4;
  bool isl = (wave < 2);
  int ctbase = (isl ? wave : wave - 2) * NCW;
  const u16* __restrict__ BT = isl ? BlT : BrT;
  u16* __restrict__ Ob = isl ? Olb : Orb;

  short8 breg[NCW][4];
  #pragma unroll
  for (int c=0;c<NCW;c++)
    #pragma unroll
    for (int t=0;t<4;t++)
      breg[c][t] = *(const short8*)(BT + ((size_t)(((ctbase+c)*4 + t)*64) + lane)*8);

  int strip0 = blockIdx.x * SPB;
  short8 ah[2][4];

  {
    const u16* p1 = Ab + (size_t)(strip0*16 + m)*128 + quad*8;
    #pragma unroll
    for (int t=0;t<4;t++) ah[0][t] = *(const short8*)(p1 + t*32);
  }

  #pragma unroll
  for (int i=0;i<SPB;i++){
    int s = strip0 + i;
    if (s >= N_STRIPS) break;
    if (i+1 < SPB && s+1 < N_STRIPS){
      const u16* p1 = Ab + (size_t)((s+1)*16 + m)*128 + quad*8;
      #pragma unroll
      for (int t=0;t<4;t++) ah[(i+1)&1][t] = *(const short8*)(p1 + t*32);
    }
    const int b = i&1;
    floatx4 acc[NCW];
    #pragma unroll
    for (int c=0;c<NCW;c++) acc[c] = (floatx4){0.f,0.f,0.f,0.f};
    #pragma unroll
    for (int t=0;t<4;t++){
      #pragma unroll
      for (int c=0;c<NCW;c++)
        acc[c] = __builtin_amdgcn_mfma_f32_16x16x32_bf16(ah[b][t], breg[c][t], acc[c], 0,0,0);
    }
    int row0 = s*16;
    #pragma unroll
    for (int c=0;c<NCW;c++)
      #pragma unroll
      for (int r=0;r<4;r++)
        Ob[(size_t)(row0 + quad*4 + r)*NLD + (ctbase+c)*16 + m] = f2bf(acc[c][r]);
  }
}

// ---------------- layer 1 fused: 4 groups x 16 lanes, shfl-broadcast indices ------
// Wave per dst. Up to 64 neighbor indices per coalesced load; per-edge index via
// __shfl. Lane l covers ch 8l..8l+7 (head = l>>2); per-head score in 2 shfl;
// cross-group combine at end. No max-subtraction (scores O(5); alpha
// shift-invariant). Output h as bf16 only (feeds gemm2 A directly).
__global__ void k_fused1(const int* __restrict__ rs, const int* __restrict__ deg,
                         const int* __restrict__ csrc, const u16* __restrict__ xlb,
                         const u16* __restrict__ xrb, const float* __restrict__ att,
                         const float* __restrict__ b1, u16* __restrict__ Hb){
  int wave = threadIdx.x >> 6;
  int lane = threadIdx.x & 63;
  int d = blockIdx.x*4 + wave;
  if (d >= N_NODESC) return;
  int g = lane >> 4;        // edge slot
  int l = lane & 15;        // channel slice: 8l..8l+7

  float xrv[8], atv[8];
  {
    ushort8v xq = *(const ushort8v*)(xrb + (size_t)d*HC + 8*l);
    #pragma unroll
    for (int j=0;j<8;j++) xrv[j] = bf2f(xq[j]);
    float4 c = *(const float4*)(att + 8*l);
    float4 e = *(const float4*)(att + 8*l + 4);
    atv[0]=c.x; atv[1]=c.y; atv[2]=c.z; atv[3]=c.w;
    atv[4]=e.x; atv[5]=e.y; atv[6]=e.z; atv[7]=e.w;
  }

  int start = rs[d], degd = deg[d];

  float acc[8];
  #pragma unroll
  for (int j=0;j<8;j++) acc[j] = 0.f;
  float den = 0.f;

  for (int base = 0; base < degd; base += 64){
    int nb = degd - base; if (nb > 64) nb = 64;
    int idx = csrc[start + base + ((lane < nb) ? lane : 0)];   // one coalesced load
    for (int i = 0; i < nb; i += 4){
      bool valid = (i + g < nb);
      int s = __shfl(idx, i + g);                 // i+g <= 63 always
      ushort8v q = *(const ushort8v*)(xlb + (size_t)s*HC + 8*l);  // 16B gather
      float xv[8];
      float sc = 0.f;
      #pragma unroll
      for (int j=0;j<8;j++){
        xv[j] = bf2f(q[j]);
        sc = fmaf(lrelu(xv[j] + xrv[j]), atv[j], sc);
      }
      sc += __shfl_xor(sc, 1);
      sc += __shfl_xor(sc, 2);          // per-head sum (4-lane span)
      float p = valid ? __expf(sc) : 0.f;
      den += p;
      #pragma unroll
      for (int j=0;j<8;j++) acc[j] = fmaf(p, xv[j], acc[j]);
    }
  }
  // cross-group combine
  #pragma unroll
  for (int j=0;j<8;j++){
    acc[j] += __shfl_xor(acc[j], 16);
    acc[j] += __shfl_xor(acc[j], 32);
  }
  den += __shfl_xor(den, 16);
  den += __shfl_xor(den, 32);

  if (g == 0){
    float bv[8];
    float4 a = *(const float4*)(b1 + 8*l);
    float4 b = *(const float4*)(b1 + 8*l + 4);
    bv[0]=a.x; bv[1]=a.y; bv[2]=a.z; bv[3]=a.w;
    bv[4]=b.x; bv[5]=b.y; bv[6]=b.z; bv[7]=b.w;
    float inv = 1.f / (den + 1e-16f);
    u16 ohv[8];
    #pragma unroll
    for (int j=0;j<8;j++){
      float o = acc[j]*inv + bv[j];
      o = (o > 0.f) ? o : (__expf(o) - 1.f);
      ohv[j] = f2bf(o);
    }
    ushort4 h0 = {ohv[0],ohv[1],ohv[2],ohv[3]}, h1 = {ohv[4],ohv[5],ohv[6],ohv[7]};
    *(ushort4*)(Hb + (size_t)d*HC + 8*l)     = h0;
    *(ushort4*)(Hb + (size_t)d*HC + 8*l + 4) = h1;
  }
}

// ---------------- layer 2 fused: 8 groups x 8 lanes, shfl-broadcast indices -------
// Lane l covers ch 8l..8l+7 (16B gather); score over 8 lanes (3 shfl); heads=1.
__global__ void k_fused2(const int* __restrict__ rs, const int* __restrict__ deg,
                         const int* __restrict__ csrc, const u16* __restrict__ xlb,
                         const u16* __restrict__ xrb, const float* __restrict__ att,
                         const float* __restrict__ b2, float* __restrict__ out){
  int wave = threadIdx.x >> 6;
  int lane = threadIdx.x & 63;
  int d = blockIdx.x*4 + wave;
  if (d >= N_NODESC) return;
  int g = lane >> 3;        // 8 edge slots
  int l = lane & 7;         // channels 8l..8l+7

  float xrv[8], atv[8];
  {
    ushort8v xq = *(const ushort8v*)(xrb + (size_t)d*OUT_CH + 8*l);
    #pragma unroll
    for (int j=0;j<8;j++) xrv[j] = bf2f(xq[j]);
    float4 c = *(const float4*)(att + 8*l);
    float4 e = *(const float4*)(att + 8*l + 4);
    atv[0]=c.x; atv[1]=c.y; atv[2]=c.z; atv[3]=c.w;
    atv[4]=e.x; atv[5]=e.y; atv[6]=e.z; atv[7]=e.w;
  }

  int start = rs[d], degd = deg[d];

  float acc[8];
  #pragma unroll
  for (int j=0;j<8;j++) acc[j] = 0.f;
  float den = 0.f;

  for (int base = 0; base < degd; base += 64){
    int nb = degd - base; if (nb > 64) nb = 64;
    int idx = csrc[start + base + ((lane < nb) ? lane : 0)];
    for (int i = 0; i < nb; i += 8){
      bool valid = (i + g < nb);
      int s = __shfl(idx, i + g);                 // i+g <= 63 always
      ushort8v q = *(const ushort8v*)(xlb + (size_t)s*OUT_CH + 8*l);  // 16B gather
      float xv[8];
      float sc = 0.f;
      #pragma unroll
      for (int j=0;j<8;j++){
        xv[j] = bf2f(q[j]);
        sc = fmaf(lrelu(xv[j] + xrv[j]), atv[j], sc);
      }
      sc += __shfl_xor(sc, 1);
      sc += __shfl_xor(sc, 2);
      sc += __shfl_xor(sc, 4);          // full 64-ch sum (8-lane span)
      float p = valid ? __expf(sc) : 0.f;
      den += p;
      #pragma unroll
      for (int j=0;j<8;j++) acc[j] = fmaf(p, xv[j], acc[j]);
    }
  }
  // cross-group combine (8 groups)
  #pragma unroll
  for (int j=0;j<8;j++){
    acc[j] += __shfl_xor(acc[j], 8);
    acc[j] += __shfl_xor(acc[j], 16);
    acc[j] += __shfl_xor(acc[j], 32);
  }
  den += __shfl_xor(den, 8);
  den += __shfl_xor(den, 16);
  den += __shfl_xor(den, 32);

  if (g == 0){
    float bv[8];
    float4 a = *(const float4*)(b2 + 8*l);
    float4 b = *(const float4*)(b2 + 8*l + 4);
    bv[0]=a.x; bv[1]=a.y; bv[2]=a.z; bv[3]=a.w;
    bv[4]=b.x; bv[5]=b.y; bv[6]=b.z; bv[7]=b.w;
    float inv = 1.f / (den + 1e-16f);
    float4 o0, o1;
    o0.x = acc[0]*inv + bv[0]; o0.y = acc[1]*inv + bv[1];
    o0.z = acc[2]*inv + bv[2]; o0.w = acc[3]*inv + bv[3];
    o1.x = acc[4]*inv + bv[4]; o1.y = acc[5]*inv + bv[5];
    o1.z = acc[6]*inv + bv[6]; o1.w = acc[7]*inv + bv[7];
    *(float4*)(out + (size_t)d*OUT_CH + 8*l)     = o0;
    *(float4*)(out + (size_t)d*OUT_CH + 8*l + 4) = o1;
  }
}

extern "C" void kernel_launch(void* const* d_in, const int* in_sizes, int n_in,
                              void* d_out, int out_size, void* d_ws, size_t ws_size,
                              hipStream_t stream) {
  const float* x    = (const float*)d_in[0];
  const int*   ei   = (const int*)d_in[1];
  const float* W1l  = (const float*)d_in[2];
  const float* W1r  = (const float*)d_in[3];
  const float* att1 = (const float*)d_in[4];
  const float* b1   = (const float*)d_in[5];
  const float* W2l  = (const float*)d_in[6];
  const float* W2r  = (const float*)d_in[7];
  const float* att2 = (const float*)d_in[8];
  const float* b2   = (const float*)d_in[9];
  float* out = (float*)d_out;

  // workspace layout (units of float; offsets multiples of 4 -> 16B aligned)
  float* ws = (float*)d_ws;
  size_t off = 0;
  u16* xl1b = (u16*)(ws + off); off += (size_t)N_NODESC*HC/2;     // bf16 [N x 128]
  u16* xr1b = (u16*)(ws + off); off += (size_t)N_NODESC*HC/2;
  u16* xl2b = (u16*)(ws + off); off += (size_t)N_NODESC*OUT_CH/2; // bf16 [N x 64]
  u16* xr2b = (u16*)(ws + off); off += (size_t)N_NODESC*OUT_CH/2;
  u16* xhb  = (u16*)(ws + off); off += (size_t)N_NODESC*HC/2;     // bf16 A for gemm1
  u16* hb   = (u16*)(ws + off); off += (size_t)N_NODESC*HC/2;     // bf16 A for gemm2
  u16* w1lh = (u16*)(ws + off); off += IN_CH*HC/2;
  u16* w1rh = (u16*)(ws + off); off += IN_CH*HC/2;
  u16* w2lh = (u16*)(ws + off); off += HC*OUT_CH/2;
  u16* w2rh = (u16*)(ws + off); off += HC*OUT_CH/2;
  int* deg    = (int*)(ws + off); off += N_NODESC;
  int* rs     = (int*)(ws + off); off += N_NODESC;
  int* cursor = (int*)(ws + off); off += N_NODESC;
  int* bsum   = (int*)(ws + off); off += 256;
  int* csrc   = (int*)(ws + off); off += E_TOT;

  // ---- zero deg (async memset) + misc (hist + prep + cast) + CSR scan/fill ----
  hipMemsetAsync(deg, 0, N_NODESC*sizeof(int), stream);
  k_misc<<<NB_HIST + NB_PREP + NB_SPLIT, 256, 0, stream>>>(
      ei, deg, x, xhb, W1l, W1r, W2l, W2r, w1lh, w1rh, w2lh, w2rh);
  k_scan_a<<<NB_SCAN, 256, 0, stream>>>(deg, rs, bsum);
  k_scan_bc<<<NB_SCAN, 256, 0, stream>>>(rs, bsum, cursor);
  k_fill<<<(E_TOT+255)/256, 256, 0, stream>>>(ei, cursor, csrc);

  const int NB_G = (N_STRIPS + 3)/4;   // SPB=4
  // ---- layer 1 ----
  k_gemm_regB<4,4><<<NB_G, 256, 0, stream>>>(xhb, w1lh, w1rh, xl1b, xr1b);
  k_fused1<<<(N_NODESC+3)/4, 256, 0, stream>>>(rs, deg, csrc, xl1b, xr1b, att1, b1, hb);

  // ---- layer 2 ----
  k_gemm_regB<2,4><<<NB_G, 256, 0, stream>>>(hb, w2lh, w2rh, xl2b, xr2b);
  k_fused2<<<(N_NODESC+3)/4, 256, 0, stream>>>(rs, deg, csrc, xl2b, xr2b, att2, b2, out);
}